// Round 4
// baseline (426.406 us; speedup 1.0000x reference)
//
#include <hip/hip_runtime.h>

// Problem constants (fixed by the reference file)
constexpr int C = 32;
constexpr int H = 128;
constexpr int W = 512;
constexpr int PAD = 40;
constexpr int D = PAD + 1;      // 41 disparity planes
constexpr int W4 = W / 4;       // 128 float4 per row
constexpr int HALF = H / 2;     // 64 rows per block (half a d-plane = 128 KB)
constexpr int NXCD = 8;
constexpr int PER_C = D * 2;    // 82 half-plane blocks per channel c
constexpr int NBLK = C * PER_C; // 2624 blocks

// out[c][d][h][w] = (w >= d) ? in1[c][h][w] * in2[c][h][w-d] : 0
//
// R4 model (from R0/R2/R3 evidence):
//  - Linear writes reach ~6.2 TB/s (fill; R2's writes were fully hidden).
//  - Plane-strided write streams cap ~2.5-2.7 TB/s regardless of 4KB (R0)
//    or 32KB (R3) run length -> each block must write ONE contiguous chunk
//    of ONE d-plane (R2's layout).
//  - R2's killer was reads: ~2048 resident blocks spanned 13+ c-slices per
//    XCD (>4MiB L2) -> 41x re-reads (1.4GB) all came from L3 at ~8TB/s.
// Fix: pin channels to XCDs. HW assigns consecutive blockIdx round-robin to
// the 8 XCDs (basis of the T1 swizzle), so with c = slot*8 + (bid&7) each
// XCD touches only 4 c-slices = 2MB of input = L2-resident forever. The 41x
// re-reads become L2 hits (~19us aggregate, hidden under stores); HBM reads
// each input byte once. Writes: 2624 blocks x 128KB contiguous each, plain
// stores (the fill's proven path). d is block-uniform -> intra-float4 shift
// specialized via template switch.
template <int RR>
__device__ __forceinline__
void half_plane(const float4* __restrict__ p1,
                const float4* __restrict__ pc,
                const float4* __restrict__ pp,
                float4* __restrict__ po,
                const bool okc, const bool okp) {
    const float4 z4 = make_float4(0.f, 0.f, 0.f, 0.f);
#pragma unroll 8
    for (int it = 0; it < HALF / 2; ++it) {   // 32 slices of 2 rows
        const float4 a   = *p1;
        const float4 cur = okc ? *pc : z4;
        const float4 prv = (RR == 0) ? z4 : (okp ? *pp : z4); // DCE'd for RR==0

        // b[k] = in2row[4*w4 + k - d]; RR compile-time -> free register picks
        float b0, b1, b2, b3;
        if      (RR == 0) { b0 = cur.x; b1 = cur.y; b2 = cur.z; b3 = cur.w; }
        else if (RR == 1) { b0 = prv.w; b1 = cur.x; b2 = cur.y; b3 = cur.z; }
        else if (RR == 2) { b0 = prv.z; b1 = prv.w; b2 = cur.x; b3 = cur.y; }
        else              { b0 = prv.y; b1 = prv.z; b2 = prv.w; b3 = cur.x; }

        float4 res;
        res.x = a.x * b0;
        res.y = a.y * b1;
        res.z = a.z * b2;
        res.w = a.w * b3;

        *po = res;                            // plain store, linear sweep

        p1 += 2 * W4; pc += 2 * W4; pp += 2 * W4; po += 2 * W4;
    }
}

__global__ __launch_bounds__(256)
void corr1d_kernel(const float* __restrict__ in1,
                   const float* __restrict__ in2,
                   float* __restrict__ out) {
    const int bid = blockIdx.x;
    const int xcd = bid & (NXCD - 1);        // presumed XCD (round-robin)
    const int g   = bid >> 3;                // [0,328)
    const int cg  = g / PER_C;               // [0,4)  c-slot on this XCD
    const int rem = g - cg * PER_C;          // [0,82)
    const int d    = rem >> 1;               // [0,41)  block-uniform
    const int half = rem & 1;                // top/bottom half of plane
    const int c    = cg * NXCD + xcd;        // [0,32): c == xcd (mod 8)

    const int t  = threadIdx.x;
    const int r  = t >> 7;                   // row within pair: 0/1
    const int w4 = t & (W4 - 1);             // float4 slot in row

    const int q  = d >> 2;                   // float4 shift
    const int I  = w4 - q;
    const bool okc = (I >= 0);
    const bool okp = (I >= 1);
    const int ic = okc ? I     : 0;          // clamp: stay inside the row
    const int ip = okp ? I - 1 : 0;

    const int h = half * HALF + r;
    const int rowBase = (c * H + h) * W4;

    const float4* p1 = (const float4*)in1 + rowBase + w4;
    const float4* pc = (const float4*)in2 + rowBase + ic;
    const float4* pp = (const float4*)in2 + rowBase + ip;
    float4*       po = (float4*)out + ((c * D + d) * H + h) * W4 + w4;

    switch (d & 3) {                         // block-uniform branch
        case 0:  half_plane<0>(p1, pc, pp, po, okc, okp); break;
        case 1:  half_plane<1>(p1, pc, pp, po, okc, okp); break;
        case 2:  half_plane<2>(p1, pc, pp, po, okc, okp); break;
        default: half_plane<3>(p1, pc, pp, po, okc, okp); break;
    }
}

extern "C" void kernel_launch(void* const* d_in, const int* in_sizes, int n_in,
                              void* d_out, int out_size, void* d_ws, size_t ws_size,
                              hipStream_t stream) {
    const float* in1 = (const float*)d_in[0];
    const float* in2 = (const float*)d_in[1];
    float* out = (float*)d_out;

    dim3 block(256);
    dim3 grid(NBLK);   // 2624 blocks: 128 KB contiguous write each, c pinned to XCD
    corr1d_kernel<<<grid, block, 0, stream>>>(in1, in2, out);
}